// Round 8
// baseline (265.789 us; speedup 1.0000x reference)
//
#include <hip/hip_runtime.h>

// Reference numpy/jnp math is UNFUSED IEEE f32 — disable FMA contraction so
// the catastrophically-cancelled det (compared against EPS=1e-7) and the
// 1/det-scaled shifts are bit-identical to the reference.
#pragma clang fp contract(off)

// Problem constants (from setup_inputs): B=2, C=4, D=6, H=512, W=512, f32.
constexpr int B_ = 2, C_ = 4, D_ = 6, H_ = 512, W_ = 512;
constexpr int HW_  = H_ * W_;        // 262144
constexpr int DHW_ = D_ * HW_;       // 1572864
constexpr int BC_  = B_ * C_;        // 8
constexpr int TOT_ = BC_ * DHW_;     // 12582912

#define EPS_ 1e-7f
#define MAX_SHIFT_ 0.6f
#define BONUS_ 10.0f
#define N_ITERS_ 5

// Native clang vector types — __builtin_nontemporal_store requires these
// (HIP_vector_type float2/int2 classes are rejected).
typedef float v2f __attribute__((ext_vector_type(2)));
typedef int   v2i __attribute__((ext_vector_type(2)));

// ---------------------------------------------------------------------------
// 3x3x3 quadratic-fit Cramer solve; p points at the (interior) center voxel.
// Op ordering mirrors the reference exactly (f32, no contraction).
__device__ __forceinline__ void solve3(const float* __restrict__ p,
                                       float& sx, float& sy, float& ss,
                                       float& gds, bool& sol)
{
    #pragma clang fp contract(off)
    float c    = p[0];
    float xp   = p[1],          xm   = p[-1];
    float yp   = p[W_],         ym   = p[-W_];
    float spv  = p[HW_],        smv  = p[-HW_];
    float xpyp = p[W_ + 1],     xmyp = p[W_ - 1];
    float xpym = p[-W_ + 1],    xmym = p[-W_ - 1];
    float xpsp = p[HW_ + 1],    xmsp = p[HW_ - 1];
    float xpsm = p[-HW_ + 1],   xmsm = p[-HW_ - 1];
    float ypsp = p[HW_ + W_],   ymsp = p[HW_ - W_];
    float ypsm = p[-HW_ + W_],  ymsm = p[-HW_ - W_];

    float gx = 0.5f * (xp - xm);
    float gy = 0.5f * (yp - ym);
    float gs = 0.5f * (spv - smv);
    float dxx = xp - 2.0f * c + xm;
    float dyy = yp - 2.0f * c + ym;
    float dss = spv - 2.0f * c + smv;
    float dxy = 0.25f * (xpyp - xmyp - xpym + xmym);
    float dxs = 0.25f * (xpsp - xmsp - xpsm + xmsm);
    float dys = 0.25f * (ypsp - ymsp - ypsm + ymsm);

    float cf00 = dyy * dss - dys * dys;
    float cf01 = dxy * dss - dys * dxs;
    float cf02 = dxy * dys - dyy * dxs;
    float det  = dxx * cf00 - dxy * cf01 + dxs * cf02;
    sol = fabsf(det) > EPS_;
    float sd = sol ? det : 1.0f;
    float r0 = -gx, r1 = -gy, r2 = -gs;
    sx = (r0 * cf00 - dxy * (r1 * dss - dys * r2) + dxs * (r1 * dys - dyy * r2)) / sd;
    sy = (dxx * (r1 * dss - dys * r2) - r0 * cf01 + dxs * (dxy * r2 - r1 * dxs)) / sd;
    ss = (dxx * (dyy * r2 - r1 * dys) - dxy * (dxy * r2 - r1 * dxs) + r0 * cf02) / sd;
    gds = gx * sx + gy * sy + gs * ss;
}

// Reference walk with EXACT early termination (bit-exact vs 5-iter reference):
//  - `valid` is monotone: once false, shifts mask to 0 forever → defaults.
//  - valid with all-zero steps = fixed point → later iterations identical.
// Overwrites coords via cb; returns y value.
__device__ __forceinline__ float walk_one(const float* __restrict__ xb,
                                          float* __restrict__ cb,
                                          int d, int h, int w, float xc)
{
    #pragma clang fp contract(off)
    int dsd = 0, dsh = 0, dsw = 0;
    bool valid = true;
    float shx = 0.0f, shy = 0.0f, shs = 0.0f, gk = 0.0f;

    #pragma unroll 1
    for (int it = 0; it < N_ITERS_; ++it) {
        int di = min(max(d + dsd, 1), D_ - 2);
        int hi = min(max(h + dsh, 1), H_ - 2);
        int wi = min(max(w + dsw, 1), W_ - 2);
        const float* p = xb + di * HW_ + hi * W_ + wi;

        float sx, sy, ssv, gds; bool sol;
        solve3(p, sx, sy, ssv, gds, sol);

        if (!sol) { valid = false; break; }   // defaults — exact

        shx = sx; shy = sy; shs = ssv; gk = gds;

        int stx = (shx > MAX_SHIFT_) ? 1 : ((shx < -MAX_SHIFT_) ? -1 : 0);
        int sty = (shy > MAX_SHIFT_) ? 1 : ((shy < -MAX_SHIFT_) ? -1 : 0);
        int sts = (shs > MAX_SHIFT_) ? 1 : ((shs < -MAX_SHIFT_) ? -1 : 0);
        dsw += stx;
        dsh += sty;
        dsd += sts;
        valid = (abs(dsd) <= 1) && (abs(dsh) <= 1) && (abs(dsw) <= 1);
        if (!valid) break;                    // radius breach — exact
        if ((stx | sty | sts) == 0) break;    // fixed point — exact
    }

    if (valid) {
        int di = min(max(d + dsd, 1), D_ - 2);
        int hi = min(max(h + dsh, 1), H_ - 2);
        int wi = min(max(w + dsw, 1), W_ - 2);
        float cur = xb[di * HW_ + hi * W_ + wi];
        __builtin_nontemporal_store((float)(d + dsd) + shs, cb);
        __builtin_nontemporal_store((float)(w + dsw) + shx, cb + DHW_);
        __builtin_nontemporal_store((float)(h + dsh) + shy, cb + 2 * DHW_);
        return (cur + 0.5f * gk) + BONUS_;
    }
    return xc + BONUS_;   // coord defaults already stored (vectorized)
}

// ---------------------------------------------------------------------------
// One fused pass, one thread per TWO voxels (x2 vectorized). Default outputs
// stream out as v2f nontemporal stores; wave-uniform ballot skips the walk
// for 88% of waves; seed lanes run the early-terminating walk and overwrite.
__global__ __launch_bounds__(256)
void AdaptiveQuadInterp3d_kernel(const v2f* __restrict__ x2,
                                 const v2i* __restrict__ m2,
                                 float* __restrict__ out)
{
    int tid  = blockIdx.x * 256 + threadIdx.x;   // 0 .. TOT/2-1
    int idx  = tid << 1;

    int w  = idx & (W_ - 1);
    int h  = (idx >> 9) & (H_ - 1);
    int t  = idx >> 18;          // bc*D + d   (HW = 2^18)
    int d  = t % D_;
    int bc = t / D_;
    int sp = idx - bc * DHW_;

    v2f xv = x2[tid];
    v2i mv = m2[tid];

    // Default coords: cs=d, cx=w,w+1, cy=h. Vector nt stores; seed lanes
    // overwrite below (same thread, same address → program-order safe).
    float* cb = out + (bc * 3) * DHW_ + sp;
    v2f csv = {(float)d, (float)d};
    v2f cxv = {(float)w, (float)(w + 1)};
    v2f cyv = {(float)h, (float)h};
    __builtin_nontemporal_store(csv, (v2f*)cb);
    __builtin_nontemporal_store(cxv, (v2f*)(cb + DHW_));
    __builtin_nontemporal_store(cyv, (v2f*)(cb + 2 * DHW_));

    v2f yv = xv;                 // y_max default = x

    // Wave-uniform skip: 0.999^128 ≈ 88% of waves have no seeds.
    if (__ballot((mv.x | mv.y) != 0) != 0ULL) {
        const float* xb = (const float*)x2 + bc * DHW_;
        if (mv.x != 0) yv.x = walk_one(xb, cb,     d, h, w,     xv.x);
        if (mv.y != 0) yv.y = walk_one(xb, cb + 1, d, h, w + 1, xv.y);
    }

    __builtin_nontemporal_store(yv, (v2f*)(out + BC_ * 3 * DHW_ + idx));
}

extern "C" void kernel_launch(void* const* d_in, const int* in_sizes, int n_in,
                              void* d_out, int out_size, void* d_ws, size_t ws_size,
                              hipStream_t stream) {
    const float* x    = (const float*)d_in[0];
    const int*   mask = (const int*)d_in[1];
    float*       out  = (float*)d_out;

    int blocks = (TOT_ / 2) / 256;   // 24576
    AdaptiveQuadInterp3d_kernel<<<blocks, 256, 0, stream>>>(
        (const v2f*)x, (const v2i*)mask, out);
}